// Round 1
// baseline (10133.393 us; speedup 1.0000x reference)
//
#include <hip/hip_runtime.h>
#include <stdint.h>
#include <math.h>

#define NB 64
#define NT 512
#define NF 128
#define NH 512
#define NO 128
#define NG 1536  // 3*NH

typedef short s16x8 __attribute__((ext_vector_type(8)));   // 8 bf16 (4 VGPRs)
typedef float f32x16 __attribute__((ext_vector_type(16))); // 32x32 MFMA acc

// ---------------- workspace layout (bytes) ----------------
#define OFF_XBF   ((size_t)0)                      // B*T*F bf16 = 8 MB
#define OFF_WOUT  ((size_t)(8u<<20))               // O*H bf16 = 128 KB
#define OFF_XP    ((size_t)(9u<<20))               // 3*2*B*3H fp32 = 2.25 MB
#define OFF_SEQ0  ((size_t)(12u<<20))              // B*T*H bf16 = 32 MB
#define OFF_SEQ1  (OFF_SEQ0 + ((size_t)32u<<20))
#define OFF_SEQ2  (OFF_SEQ1 + ((size_t)32u<<20))
#define OFF_FLAGS (OFF_SEQ2 + ((size_t)32u<<20))   // 192 u32

#define SMEM_BYTES (96*1024 + 512 + 8192)          // weights + biases + r/z tiles

__device__ __forceinline__ unsigned short f2bf(float f) {
  unsigned int u = __float_as_uint(f);
  u += 0x7fffu + ((u >> 16) & 1u);   // round-to-nearest-even
  return (unsigned short)(u >> 16);
}

__device__ __forceinline__ void waitge(unsigned int* p, unsigned int want) {
  // relaxed poll (no per-poll cache inv), one acquire at the end
  while (__hip_atomic_load(p, __ATOMIC_RELAXED, __HIP_MEMORY_SCOPE_AGENT) < want)
    __builtin_amdgcn_s_sleep(2);
  (void)__hip_atomic_load(p, __ATOMIC_ACQUIRE, __HIP_MEMORY_SCOPE_AGENT);
}

// ---------------------------------------------------------------------------
// Persistent wavefront-pipelined GRU. 192 WGs = 3 layers x (32 xp + 32 rec).
// Each WG: 3 waves (one per gate r/z/n), 32 h-cols x 32 batch rows.
// Weights live in LDS in MFMA B-fragment order (packed once at start).
// Sync: monotonic per-WG progress flags in d_ws (device-scope atomics).
// ---------------------------------------------------------------------------
__global__ __launch_bounds__(192, 1)
void gru_persist(const unsigned short* __restrict__ xbf,
                 unsigned short* __restrict__ seq0,
                 unsigned short* __restrict__ seq1,
                 unsigned short* __restrict__ seq2,
                 float* __restrict__ xpbuf,
                 unsigned int* __restrict__ flags,
                 const float* __restrict__ Wih0, const float* __restrict__ Whh0,
                 const float* __restrict__ bih0, const float* __restrict__ bhh0,
                 const float* __restrict__ Wih1, const float* __restrict__ Whh1,
                 const float* __restrict__ bih1, const float* __restrict__ bhh1,
                 const float* __restrict__ Wih2, const float* __restrict__ Whh2,
                 const float* __restrict__ bih2, const float* __restrict__ bhh2)
{
  extern __shared__ char smem[];
  unsigned short* wlds   = (unsigned short*)smem;            // <= 96 KB
  float*          biasL  = (float*)(smem + 96*1024);         // 96 floats
  float*          rzL    = (float*)(smem + 96*1024 + 512);   // 2*32*32 floats

  const int tid  = threadIdx.x;
  const int wid  = tid >> 6;      // gate: 0=r 1=z 2=n
  const int lane = tid & 63;
  const int col  = lane & 31;
  const int khi  = lane >> 5;

  const int wg   = blockIdx.x;
  const int l    = wg >> 6;          // layer 0..2
  const int rr   = wg & 63;
  const int kind = rr >> 5;          // 0 = xp (input proj), 1 = rec
  const int q    = rr & 31;
  const int c0   = (q >> 1) * 32;    // h-col slice base
  const int bh   = q & 1;
  const int b0   = bh * 32;          // batch slice base

  const float* Wsrc; const float* bsrc; int K;
  const unsigned short* Abase; int rowlen;
  unsigned short* seqw = (l==0) ? seq0 : (l==1) ? seq1 : seq2;
  if (kind == 1) {
    Wsrc = (l==0)?Whh0:(l==1)?Whh1:Whh2;
    bsrc = (l==0)?bhh0:(l==1)?bhh1:bhh2;
    K = NH; Abase = seqw; rowlen = NH;
  } else {
    Wsrc = (l==0)?Wih0:(l==1)?Wih1:Wih2;
    bsrc = (l==0)?bih0:(l==1)?bih1:bih2;
    K = (l==0)?NF:NH;
    Abase = (l==0)? xbf : ((l==1)? seq0 : seq1);
    rowlen = K;
  }
  const int KT = K >> 4;  // 16-wide k-tiles: 32 (K=512) or 8 (K=128)

  // ---- pack weight slice into LDS, bf16, B-fragment order ----
  // b_frag(gate g, ktile kt): lane holds B[k=kt*16+(lane>>5)*8+j][n=lane&31]
  //                           = W[g*NH + c0 + n][k]
  {
    const int total = 3 * KT * 512;        // elements
    for (int i = tid; i < total; i += 192) {
      int j  = i & 7;
      int ln = (i >> 3) & 63;
      int gk = i >> 9;                      // g*KT + kt
      int n  = ln & 31;
      int k  = (gk % KT)*16 + ((ln >> 5) << 3) + j;
      int g  = gk / KT;
      float v = Wsrc[(size_t)(g*NH + c0 + n) * K + k];
      wlds[(size_t)gk*512 + ln*8 + j] = f2bf(v);
    }
    if (tid < 96) biasL[tid] = bsrc[(tid >> 5)*NH + c0 + (tid & 31)];
  }
  __syncthreads();

  const unsigned short* wrow = wlds + (size_t)(wid*KT)*512 + lane*8;

  if (kind == 1) {
    // ------------------------- recurrence WG -------------------------
    float hprev[16];
    #pragma unroll
    for (int i = 0; i < 16; ++i) hprev[i] = 0.f;

    for (int t = 0; t < NT; ++t) {
      // peers (all col-slices, same layer+batch) must have finished t-1
      if (t > 0 && tid < 16) waitge(&flags[l*64 + 32 + tid*2 + bh], (unsigned)t);
      // our xp producer must have finished t
      if (tid == 64) waitge(&flags[wg - 32], (unsigned)(t+1));
      __syncthreads();

      f32x16 acc;
      #pragma unroll
      for (int i = 0; i < 16; ++i) acc[i] = 0.f;

      if (t > 0) {
        const unsigned short* arow =
            Abase + ((size_t)(b0 + col) * NT + (t-1)) * NH + (khi << 3);
        #pragma unroll
        for (int kt = 0; kt < 32; ++kt) {           // K = 512
          s16x8 a = *(const s16x8*)(arow + kt*16);
          s16x8 b = *(const s16x8*)(wrow + kt*512);
          acc = __builtin_amdgcn_mfma_f32_32x32x16_bf16(a, b, acc, 0, 0, 0);
        }
      }

      const float* xps = xpbuf + (size_t)((l*2 + (t & 1)) * NB) * NG;

      if (wid < 2) {            // r and z gates -> sigmoid -> LDS
        float* tile = rzL + wid*1024;
        #pragma unroll
        for (int r = 0; r < 16; ++r) {
          int row = (r & 3) + ((r >> 2) << 3) + (khi << 2);
          float xp  = xps[(size_t)(b0+row)*NG + wid*NH + c0 + col];
          float pre = acc[r] + xp + biasL[wid*32 + col];
          tile[row*32 + col] = 1.f / (1.f + __expf(-pre));
        }
      }
      float hn[16];
      if (wid == 2) {
        #pragma unroll
        for (int r = 0; r < 16; ++r) hn[r] = acc[r] + biasL[64 + col];
      }
      __syncthreads();

      if (wid == 2) {           // n gate + state update (fp32 master in regs)
        #pragma unroll
        for (int r = 0; r < 16; ++r) {
          int row = (r & 3) + ((r >> 2) << 3) + (khi << 2);
          float xn = xps[(size_t)(b0+row)*NG + 2*NH + c0 + col];
          float rt = rzL[row*32 + col];
          float zt = rzL[1024 + row*32 + col];
          float nv = tanhf(xn + rt*hn[r]);
          float hv = (1.f - zt)*nv + zt*hprev[r];
          hprev[r] = hv;
          seqw[((size_t)(b0+row)*NT + t)*NH + c0 + col] = f2bf(hv);
        }
        __threadfence();        // agent-scope: push h(t) to coherence point
      }
      __syncthreads();
      if (tid == 0)
        __hip_atomic_store(&flags[wg], (unsigned)(t+1),
                           __ATOMIC_RELEASE, __HIP_MEMORY_SCOPE_AGENT);
    }
  } else {
    // ------------------------ input-projection WG ------------------------
    for (int t = 0; t < NT; ++t) {
      // producers: layer l-1 rec WGs (same batch half) finished t
      if (l > 0 && tid < 16) waitge(&flags[(l-1)*64 + 32 + tid*2 + bh], (unsigned)(t+1));
      // backpressure: our rec consumer finished t-2 (slot t&1 free)
      if (t >= 2 && tid == 64) waitge(&flags[wg + 32], (unsigned)(t-1));
      __syncthreads();

      f32x16 acc;
      #pragma unroll
      for (int i = 0; i < 16; ++i) acc[i] = 0.f;

      const unsigned short* arow =
          Abase + ((size_t)(b0 + col) * NT + t) * rowlen + (khi << 3);
      #pragma unroll 4
      for (int kt = 0; kt < KT; ++kt) {
        s16x8 a = *(const s16x8*)(arow + kt*16);
        s16x8 b = *(const s16x8*)(wrow + kt*512);
        acc = __builtin_amdgcn_mfma_f32_32x32x16_bf16(a, b, acc, 0, 0, 0);
      }

      float* xpd = xpbuf + (size_t)((l*2 + (t & 1)) * NB) * NG;
      #pragma unroll
      for (int r = 0; r < 16; ++r) {
        int row = (r & 3) + ((r >> 2) << 3) + (khi << 2);
        xpd[(size_t)(b0+row)*NG + wid*NH + c0 + col] = acc[r] + biasL[wid*32 + col];
      }
      __threadfence();
      __syncthreads();
      if (tid == 0)
        __hip_atomic_store(&flags[wg], (unsigned)(t+1),
                           __ATOMIC_RELEASE, __HIP_MEMORY_SCOPE_AGENT);
    }
  }
}

// ---------------- head GEMM: out[bt][o] = seq2[bt][:] . Wout[o][:] + bout ----
__global__ __launch_bounds__(256)
void head_gemm(const unsigned short* __restrict__ seq2,
               const unsigned short* __restrict__ woutb,
               const float* __restrict__ bout,
               float* __restrict__ out)
{
  int tid = threadIdx.x;
  int wv = tid >> 6, lane = tid & 63;
  int col = lane & 31, khi = lane >> 5;
  int id = blockIdx.x*4 + wv;
  int mt = id >> 2, nt = id & 3;
  int m0 = mt*32, n0 = nt*32;
  const unsigned short* arow = seq2  + (size_t)(m0 + col)*NH + (khi << 3);
  const unsigned short* brow = woutb + (size_t)(n0 + col)*NH + (khi << 3);
  f32x16 acc;
  #pragma unroll
  for (int i = 0; i < 16; ++i) acc[i] = 0.f;
  #pragma unroll 8
  for (int kt = 0; kt < 32; ++kt) {
    s16x8 a = *(const s16x8*)(arow + kt*16);
    s16x8 b = *(const s16x8*)(brow + kt*16);
    acc = __builtin_amdgcn_mfma_f32_32x32x16_bf16(a, b, acc, 0, 0, 0);
  }
  float bo = bout[n0 + col];
  #pragma unroll
  for (int r = 0; r < 16; ++r) {
    int row = (r & 3) + ((r >> 2) << 3) + (khi << 2);
    out[(size_t)(m0 + row)*NO + n0 + col] = acc[r] + bo;
  }
}

__global__ void cast_f32_bf16(const float* __restrict__ src,
                              unsigned short* __restrict__ dst, int n) {
  int i = blockIdx.x*blockDim.x + threadIdx.x;
  int stride = gridDim.x*blockDim.x;
  for (; i < n; i += stride) dst[i] = f2bf(src[i]);
}

extern "C" void kernel_launch(void* const* d_in, const int* in_sizes, int n_in,
                              void* d_out, int out_size, void* d_ws, size_t ws_size,
                              hipStream_t stream) {
  (void)in_sizes; (void)n_in; (void)out_size; (void)ws_size;
  const float* x    = (const float*)d_in[0];
  const float* Wih0 = (const float*)d_in[1];
  const float* Whh0 = (const float*)d_in[2];
  const float* bih0 = (const float*)d_in[3];
  const float* bhh0 = (const float*)d_in[4];
  const float* Wih1 = (const float*)d_in[5];
  const float* Whh1 = (const float*)d_in[6];
  const float* bih1 = (const float*)d_in[7];
  const float* bhh1 = (const float*)d_in[8];
  const float* Wih2 = (const float*)d_in[9];
  const float* Whh2 = (const float*)d_in[10];
  const float* bih2 = (const float*)d_in[11];
  const float* bhh2 = (const float*)d_in[12];
  const float* Wout = (const float*)d_in[13];
  const float* bout = (const float*)d_in[14];

  char* ws = (char*)d_ws;
  unsigned short* xbf  = (unsigned short*)(ws + OFF_XBF);
  unsigned short* wob  = (unsigned short*)(ws + OFF_WOUT);
  float*          xpb  = (float*)(ws + OFF_XP);
  unsigned short* seq0 = (unsigned short*)(ws + OFF_SEQ0);
  unsigned short* seq1 = (unsigned short*)(ws + OFF_SEQ1);
  unsigned short* seq2 = (unsigned short*)(ws + OFF_SEQ2);
  unsigned int*   flg  = (unsigned int*)(ws + OFF_FLAGS);

  // allow >64KB dynamic LDS (idempotent; not a stream op, capture-safe)
  (void)hipFuncSetAttribute((const void*)gru_persist,
                            hipFuncAttributeMaxDynamicSharedMemorySize, 160*1024);

  hipMemsetAsync(ws + OFF_FLAGS, 0, 4096, stream);
  cast_f32_bf16<<<512, 256, 0, stream>>>(x, xbf, NB*NT*NF);
  cast_f32_bf16<<<64, 256, 0, stream>>>(Wout, wob, NO*NH);
  gru_persist<<<192, 192, SMEM_BYTES, stream>>>(xbf, seq0, seq1, seq2, xpb, flg,
      Wih0, Whh0, bih0, bhh0, Wih1, Whh1, bih1, bhh1, Wih2, Whh2, bih2, bhh2);
  head_gemm<<<1024, 256, 0, stream>>>(seq2, wob, bout, (float*)d_out);
}

// Round 2
// 3167.900 us; speedup vs baseline: 3.1988x; 3.1988x over previous
//
#include <hip/hip_runtime.h>
#include <stdint.h>
#include <math.h>

#define NB 64
#define NT 512
#define NF 128
#define NH 512
#define NO 128

typedef short  s16x8  __attribute__((ext_vector_type(8)));   // 8 bf16
typedef float  f32x4  __attribute__((ext_vector_type(4)));   // 16x16 acc
typedef float  f32x16 __attribute__((ext_vector_type(16)));  // 32x32 acc (head)

// ---------------- workspace layout (bytes) ----------------
#define OFF_XBF   ((size_t)0)                      // B*T*F bf16 = 8 MB
#define OFF_WOUT  ((size_t)(8u<<20))               // O*H bf16 = 128 KB
#define OFF_SEQ0  ((size_t)(12u<<20))              // B*T*H bf16 = 32 MB
#define OFF_SEQ1  (OFF_SEQ0 + ((size_t)32u<<20))
#define OFF_SEQ2  (OFF_SEQ1 + ((size_t)32u<<20))
#define OFF_FLAGS (OFF_SEQ2 + ((size_t)32u<<20))   // 192 u32

__device__ __forceinline__ unsigned short f2bf(float f) {
  unsigned int u = __float_as_uint(f);
  u += 0x7fffu + ((u >> 16) & 1u);   // RNE
  return (unsigned short)(u >> 16);
}

// relaxed agent poll: goes to coherence point, NO buffer_inv (that was the 10ms)
__device__ __forceinline__ void waitge(unsigned int* p, unsigned int want) {
  while (__hip_atomic_load(p, __ATOMIC_RELAXED, __HIP_MEMORY_SCOPE_AGENT) < want)
    __builtin_amdgcn_s_sleep(1);
}

// write-through store to IC (sc0 sc1): visible agent-wide after vmcnt(0),
// no L2 allocate -> no stale-line hazard, no wbl2 fence needed.
__device__ __forceinline__ void store_short_wt(unsigned short* p, unsigned short v) {
  unsigned int vv = v;
  asm volatile("global_store_short %0, %1, off sc0 sc1" :: "v"(p), "v"(vv) : "memory");
}

__device__ __forceinline__ float sigmoid_f(float x) { return 1.f / (1.f + __expf(-x)); }
__device__ __forceinline__ float tanh_f(float x)    { return 1.f - 2.f / (__expf(2.f*x) + 1.f); }

// ---------------------------------------------------------------------------
// Persistent wavefront-pipelined GRU, zero cache-flushing.
// 192 WGs = 3 layers x 4 batch-quarters x 16 col-slices. 384 thr = 6 waves:
//   waves 0-2: rec gates r/z/n (Whh slice in VGPRs), step t
//   waves 3-5: xp gates r/z/n (Wih slice in VGPRs), step t+1 (one ahead)
// h exchanged through IC (write-through stores + relaxed flags). xp staged in LDS.
// ---------------------------------------------------------------------------
__global__ __launch_bounds__(384, 2)
void gru_persist(const unsigned short* __restrict__ xbf,
                 unsigned short* __restrict__ seq0,
                 unsigned short* __restrict__ seq1,
                 unsigned short* __restrict__ seq2,
                 unsigned int* __restrict__ flags,
                 const float* __restrict__ Wih0, const float* __restrict__ Whh0,
                 const float* __restrict__ bih0, const float* __restrict__ bhh0,
                 const float* __restrict__ Wih1, const float* __restrict__ Whh1,
                 const float* __restrict__ bih1, const float* __restrict__ bhh1,
                 const float* __restrict__ Wih2, const float* __restrict__ Whh2,
                 const float* __restrict__ bih2, const float* __restrict__ bhh2)
{
  __shared__ float xpL[2][3][16][33];  // [slot][gate][row][col] xp incl bih
  __shared__ float rzL[2][16][33];     // [r/z][row][col] sigmoids

  const int tid  = threadIdx.x;
  const int wid  = tid >> 6;
  const int lane = tid & 63;
  const int col  = lane & 15;     // n / m index
  const int quad = lane >> 4;     // k-group / row-quad

  const int wg = blockIdx.x;
  const int l  = wg >> 6;          // layer 0..2
  const int rr = wg & 63;
  const int bq = rr >> 4;          // batch quarter
  const int cq = rr & 15;          // col slice
  const int c0 = cq * 32;
  const int b0 = bq * 16;

  unsigned short* seqw = (l==0) ? seq0 : (l==1) ? seq1 : seq2;
  const unsigned short* seqr = (l==1) ? seq0 : (l==2) ? seq1 : (const unsigned short*)0;

  const bool isrec = (wid < 3);
  const int  g     = isrec ? wid : wid - 3;

  const float* Whh = (l==0)?Whh0:(l==1)?Whh1:Whh2;
  const float* Wih = (l==0)?Wih0:(l==1)?Wih1:Wih2;
  const float* bhh = (l==0)?bhh0:(l==1)?bhh1:bhh2;
  const float* bih = (l==0)?bih0:(l==1)?bih1:bih2;

  const float* Wsrc = isrec ? Whh : Wih;
  const int K  = isrec ? NH : ((l==0) ? NF : NH);
  const int KT = K >> 5;                 // 32-wide k-tiles: 16 or 4
  const int xprow = (l==0) ? NF : NH;    // xp A row length

  // ---- preload weight slice into VGPRs (B-frag order), bf16 ----
  s16x8 wr0[16], wr1[16];
  #pragma unroll
  for (int kt = 0; kt < 16; ++kt) {
    if (kt < KT) {
      const float* s0 = Wsrc + (size_t)(g*NH + c0 +      col) * K + kt*32 + quad*8;
      const float* s1 = Wsrc + (size_t)(g*NH + c0 + 16 + col) * K + kt*32 + quad*8;
      s16x8 w0, w1;
      #pragma unroll
      for (int j = 0; j < 8; ++j) { w0[j] = (short)f2bf(s0[j]); w1[j] = (short)f2bf(s1[j]); }
      wr0[kt] = w0; wr1[kt] = w1;
    } else { wr0[kt] = (s16x8)0; wr1[kt] = (s16x8)0; }
  }
  const float* bb = isrec ? bhh : bih;
  const float bias0 = bb[g*NH + c0 +      col];
  const float bias1 = bb[g*NH + c0 + 16 + col];

  unsigned int* peer = flags + l*64 + bq*16;                       // same layer+bq
  unsigned int* prev = (l > 0) ? (flags + (l-1)*64 + bq*16) : (unsigned int*)0;

  // ---- prologue: xp(0) into slot 0 ----
  if (!isrec) {
    if (l > 0 && lane < 16) waitge(prev + lane, 1u);
    asm volatile("" ::: "memory");
    f32x4 a0 = {0.f,0.f,0.f,0.f}, a1 = {0.f,0.f,0.f,0.f};
    const unsigned short* ar = (l==0)
        ? xbf  + (size_t)(b0+col)*NT*NF + quad*8
        : seqr + (size_t)(b0+col)*NT*NH + quad*8;
    #pragma unroll
    for (int kt = 0; kt < 16; ++kt) if (kt < KT) {
      s16x8 a = *(const s16x8*)(ar + kt*32);
      a0 = __builtin_amdgcn_mfma_f32_16x16x32_bf16(a, wr0[kt], a0, 0, 0, 0);
      a1 = __builtin_amdgcn_mfma_f32_16x16x32_bf16(a, wr1[kt], a1, 0, 0, 0);
    }
    #pragma unroll
    for (int i = 0; i < 4; ++i) {
      int row = quad*4 + i;
      xpL[0][g][row][col]      = a0[i] + bias0;
      xpL[0][g][row][col + 16] = a1[i] + bias1;
    }
  }
  __syncthreads();

  float hp0[4] = {0.f,0.f,0.f,0.f}, hp1[4] = {0.f,0.f,0.f,0.f};  // n-wave h state

  for (int t = 0; t < NT; ++t) {
    const int slot  = t & 1;
    const int nslot = slot ^ 1;

    f32x4 a0 = {0.f,0.f,0.f,0.f}, a1 = {0.f,0.f,0.f,0.f};

    // ---------------- phase 1 ----------------
    if (isrec) {
      if (t > 0) {
        if (lane < 16) waitge(peer + lane, (unsigned)t);
        asm volatile("" ::: "memory");
        const unsigned short* ar = seqw + ((size_t)(b0+col)*NT + (t-1))*NH + quad*8;
        #pragma unroll
        for (int kt = 0; kt < 16; ++kt) {
          s16x8 a = *(const s16x8*)(ar + kt*32);
          a0 = __builtin_amdgcn_mfma_f32_16x16x32_bf16(a, wr0[kt], a0, 0, 0, 0);
          a1 = __builtin_amdgcn_mfma_f32_16x16x32_bf16(a, wr1[kt], a1, 0, 0, 0);
        }
      }
      if (g < 2) {       // r/z: sigmoid -> LDS
        #pragma unroll
        for (int i = 0; i < 4; ++i) {
          int row = quad*4 + i;
          float p0 = a0[i] + xpL[slot][g][row][col]      + bias0;
          float p1 = a1[i] + xpL[slot][g][row][col + 16] + bias1;
          rzL[g][row][col]      = sigmoid_f(p0);
          rzL[g][row][col + 16] = sigmoid_f(p1);
        }
      } else {           // n: keep pre-activation hn in acc regs (+bhh_n)
        #pragma unroll
        for (int i = 0; i < 4; ++i) { a0[i] += bias0; a1[i] += bias1; }
      }
    } else {             // xp waves: compute xp(t+1)
      if (t + 1 < NT) {
        if (l > 0 && lane < 16) waitge(prev + lane, (unsigned)(t + 2));
        asm volatile("" ::: "memory");
        const unsigned short* ar = (l==0)
            ? xbf  + ((size_t)(b0+col)*NT + (t+1))*NF + quad*8
            : seqr + ((size_t)(b0+col)*NT + (t+1))*NH + quad*8;
        #pragma unroll
        for (int kt = 0; kt < 16; ++kt) if (kt < KT) {
          s16x8 a = *(const s16x8*)(ar + kt*32);
          a0 = __builtin_amdgcn_mfma_f32_16x16x32_bf16(a, wr0[kt], a0, 0, 0, 0);
          a1 = __builtin_amdgcn_mfma_f32_16x16x32_bf16(a, wr1[kt], a1, 0, 0, 0);
        }
      }
    }
    __syncthreads();   // B1: rz ready; xp accs computed

    // ---------------- phase 2 ----------------
    if (wid == 2) {      // n-wave: gate combine, h update, IC store, flag
      #pragma unroll
      for (int i = 0; i < 4; ++i) {
        int row = quad*4 + i;
        float xn0 = xpL[slot][2][row][col];
        float xn1 = xpL[slot][2][row][col + 16];
        float rt0 = rzL[0][row][col],      rt1 = rzL[0][row][col + 16];
        float zt0 = rzL[1][row][col],      zt1 = rzL[1][row][col + 16];
        float nv0 = tanh_f(xn0 + rt0 * a0[i]);
        float nv1 = tanh_f(xn1 + rt1 * a1[i]);
        float h0 = (1.f - zt0)*nv0 + zt0*hp0[i];
        float h1 = (1.f - zt1)*nv1 + zt1*hp1[i];
        hp0[i] = h0; hp1[i] = h1;
        unsigned short* p = seqw + ((size_t)(b0+row)*NT + t)*NH + c0 + col;
        store_short_wt(p,      f2bf(h0));
        store_short_wt(p + 16, f2bf(h1));
      }
      asm volatile("s_waitcnt vmcnt(0)" ::: "memory");   // h visible at IC
      if (lane == 0)
        __hip_atomic_store(&flags[wg], (unsigned)(t + 1),
                           __ATOMIC_RELAXED, __HIP_MEMORY_SCOPE_AGENT);
    } else if (!isrec && t + 1 < NT) {   // xp: regs -> LDS slot t+1
      #pragma unroll
      for (int i = 0; i < 4; ++i) {
        int row = quad*4 + i;
        xpL[nslot][g][row][col]      = a0[i] + bias0;
        xpL[nslot][g][row][col + 16] = a1[i] + bias1;
      }
    }
    __syncthreads();   // B2: xp slot ready for next iter
  }
}

// ---------------- head GEMM: out[bt][o] = seq2[bt][:] . Wout[o][:] + bout ----
__global__ __launch_bounds__(256)
void head_gemm(const unsigned short* __restrict__ seq2,
               const unsigned short* __restrict__ woutb,
               const float* __restrict__ bout,
               float* __restrict__ out)
{
  int tid = threadIdx.x;
  int wv = tid >> 6, lane = tid & 63;
  int col = lane & 31, khi = lane >> 5;
  int id = blockIdx.x*4 + wv;
  int mt = id >> 2, nt = id & 3;
  int m0 = mt*32, n0 = nt*32;
  const unsigned short* arow = seq2  + (size_t)(m0 + col)*NH + (khi << 3);
  const unsigned short* brow = woutb + (size_t)(n0 + col)*NH + (khi << 3);
  f32x16 acc;
  #pragma unroll
  for (int i = 0; i < 16; ++i) acc[i] = 0.f;
  #pragma unroll 8
  for (int kt = 0; kt < 32; ++kt) {
    s16x8 a = *(const s16x8*)(arow + kt*16);
    s16x8 b = *(const s16x8*)(brow + kt*16);
    acc = __builtin_amdgcn_mfma_f32_32x32x16_bf16(a, b, acc, 0, 0, 0);
  }
  float bo = bout[n0 + col];
  #pragma unroll
  for (int r = 0; r < 16; ++r) {
    int row = (r & 3) + ((r >> 2) << 3) + (khi << 2);
    out[(size_t)(m0 + row)*NO + n0 + col] = acc[r] + bo;
  }
}

__global__ void cast_f32_bf16(const float* __restrict__ src,
                              unsigned short* __restrict__ dst, int n) {
  int i = blockIdx.x*blockDim.x + threadIdx.x;
  int stride = gridDim.x*blockDim.x;
  for (; i < n; i += stride) dst[i] = f2bf(src[i]);
}

extern "C" void kernel_launch(void* const* d_in, const int* in_sizes, int n_in,
                              void* d_out, int out_size, void* d_ws, size_t ws_size,
                              hipStream_t stream) {
  (void)in_sizes; (void)n_in; (void)out_size; (void)ws_size;
  const float* x    = (const float*)d_in[0];
  const float* Wih0 = (const float*)d_in[1];
  const float* Whh0 = (const float*)d_in[2];
  const float* bih0 = (const float*)d_in[3];
  const float* bhh0 = (const float*)d_in[4];
  const float* Wih1 = (const float*)d_in[5];
  const float* Whh1 = (const float*)d_in[6];
  const float* bih1 = (const float*)d_in[7];
  const float* bhh1 = (const float*)d_in[8];
  const float* Wih2 = (const float*)d_in[9];
  const float* Whh2 = (const float*)d_in[10];
  const float* bih2 = (const float*)d_in[11];
  const float* bhh2 = (const float*)d_in[12];
  const float* Wout = (const float*)d_in[13];
  const float* bout = (const float*)d_in[14];

  char* ws = (char*)d_ws;
  unsigned short* xbf  = (unsigned short*)(ws + OFF_XBF);
  unsigned short* wob  = (unsigned short*)(ws + OFF_WOUT);
  unsigned short* seq0 = (unsigned short*)(ws + OFF_SEQ0);
  unsigned short* seq1 = (unsigned short*)(ws + OFF_SEQ1);
  unsigned short* seq2 = (unsigned short*)(ws + OFF_SEQ2);
  unsigned int*   flg  = (unsigned int*)(ws + OFF_FLAGS);

  hipMemsetAsync(ws + OFF_FLAGS, 0, 4096, stream);
  cast_f32_bf16<<<512, 256, 0, stream>>>(x, xbf, NB*NT*NF);
  cast_f32_bf16<<<64, 256, 0, stream>>>(Wout, wob, NO*NH);
  gru_persist<<<192, 384, 0, stream>>>(xbf, seq0, seq1, seq2, flg,
      Wih0, Whh0, bih0, bhh0, Wih1, Whh1, bih1, bhh1, Wih2, Whh2, bih2, bhh2);
  head_gemm<<<1024, 256, 0, stream>>>(seq2, wob, bout, (float*)d_out);
}